// Round 4
// baseline (1073.468 us; speedup 1.0000x reference)
//
#include <hip/hip_runtime.h>

// ---------------------------------------------------------------------------
// Transformer_16784732193201 — round 4
// Changes vs r3: LN/BN/addpos fused into GEMM epilogues.
//  - gemm_ln (BM=64,BN=256 full-row): O-proj & FFN2 write x_new (fp32) AND
//    LayerNorm(x_new) bf16 (or BatchNorm for last layer) in one pass.
//  - addpos_ln: x+pos -> xbuf and LN1(layer0) -> bufA in one pass.
// ws layout:
//   xbuf  fp32 [82944,256]               @ 0          (84,934,656 B)
//   bufA  bf16 [82944,256]               @ 84934656   (42,467,328 B)
//   bufB  bf16 [82944,768]               @ 127401984  (127,401,984 B)
//   weights bf16 + fused bias            @ 254803968  (~3.2 MB)
// ---------------------------------------------------------------------------

typedef __attribute__((ext_vector_type(4))) float f32x4;
typedef __attribute__((ext_vector_type(8))) short s16x8;
typedef __attribute__((ext_vector_type(4))) unsigned short u16x4;
typedef __attribute__((ext_vector_type(8))) unsigned short u16x8;

__device__ __forceinline__ float bf2f(unsigned short u) {
  unsigned int v = ((unsigned int)u) << 16;
  return __builtin_bit_cast(float, v);
}
__device__ __forceinline__ unsigned short f2bf(float f) {
  unsigned int u = __builtin_bit_cast(unsigned int, f);
  u += 0x7fffu + ((u >> 16) & 1u);
  return (unsigned short)(u >> 16);
}

#define GLD16(gp, lp)                                                       \
  __builtin_amdgcn_global_load_lds(                                         \
      (const __attribute__((address_space(1))) void*)(gp),                  \
      (__attribute__((address_space(3))) void*)(lp), 16, 0, 0)

// ---------------------------------------------------------------------------
// Generic bf16 GEMM:  C[m,n] = sum_k A[m,k] * W[n,k]  (+bias, epilogue)
// EPI: 0 = bias -> bf16 ; 1 = bias+relu -> bf16 ; 3 = bias -> f32
// BM=128, BK=64, 4 waves as 2x2. T2 XOR-swizzled LDS; XCD-swizzled 1-D grid.
// ---------------------------------------------------------------------------
template <int BN, int EPI, int NY>
__global__ __launch_bounds__(256) void gemm_bt(
    const unsigned short* __restrict__ A, const unsigned short* __restrict__ W,
    const float* __restrict__ bias, void* __restrict__ Cout, int K, int ldc,
    int n_valid, int nW) {
  constexpr int BM = 128, BK = 64;
  constexpr int WN = BN / 2;
  constexpr int FM = 4, FN = WN / 16;
  __shared__ unsigned short Alds[BM * BK];
  __shared__ unsigned short Blds[BN * BK];

  const int tid = threadIdx.x, wave = tid >> 6, lane = tid & 63;
  const int nwg = gridDim.x;
  const int swz = (blockIdx.x & 7) * (nwg >> 3) + (blockIdx.x >> 3);
  const int row0 = (swz / NY) * BM, ncol0 = (swz % NY) * BN;
  const int wr = wave >> 1, wc = wave & 1;
  const int fr = lane & 15, g4 = lane >> 4, ko = g4 * 8;
  const int swr = (fr & 7) << 3;
  const int l8 = lane >> 3;
  const int lkS = ((lane & 7) ^ l8) * 8;

  f32x4 acc[FM][FN];
#pragma unroll
  for (int i = 0; i < FM; ++i)
#pragma unroll
    for (int j = 0; j < FN; ++j) acc[i][j] = (f32x4)0.f;

  const int nkt = K / BK;
  for (int kt = 0; kt < nkt; ++kt) {
    __syncthreads();
#pragma unroll
    for (int j = 0; j < 4; ++j) {
      int ci = wave * 4 + j;
      int arow = row0 + ci * 8 + l8;
      const unsigned short* src = A + (size_t)arow * K + kt * BK + lkS;
      GLD16(src, &Alds[ci * 512]);
    }
#pragma unroll
    for (int j = 0; j < BN / 32; ++j) {
      int ci = wave * (BN / 32) + j;
      int brow = ncol0 + ci * 8 + l8;
      if (brow >= nW) brow = nW - 1;
      const unsigned short* src = W + (size_t)brow * K + kt * BK + lkS;
      GLD16(src, &Blds[ci * 512]);
    }
    __syncthreads();
#pragma unroll
    for (int kk = 0; kk < 2; ++kk) {
      s16x8 af[FM], bfr[FN];
#pragma unroll
      for (int i = 0; i < FM; ++i)
        af[i] = *(const s16x8*)&Alds[(wr * 64 + i * 16 + fr) * BK + ((kk * 32 + ko) ^ swr)];
#pragma unroll
      for (int j = 0; j < FN; ++j)
        bfr[j] = *(const s16x8*)&Blds[(wc * WN + j * 16 + fr) * BK + ((kk * 32 + ko) ^ swr)];
#pragma unroll
      for (int i = 0; i < FM; ++i)
#pragma unroll
        for (int j = 0; j < FN; ++j)
          acc[i][j] =
              __builtin_amdgcn_mfma_f32_16x16x32_bf16(af[i], bfr[j], acc[i][j], 0, 0, 0);
    }
  }

  const int cr = g4 * 4, cc = lane & 15;
#pragma unroll
  for (int i = 0; i < FM; ++i) {
#pragma unroll
    for (int j = 0; j < FN; ++j) {
      int col = ncol0 + wc * WN + j * 16 + cc;
      if (col >= n_valid) continue;
      float bv = bias[col];
#pragma unroll
      for (int r = 0; r < 4; ++r) {
        int row = row0 + wr * 64 + i * 16 + cr + r;
        float v = acc[i][j][r] + bv;
        if constexpr (EPI == 1) v = fmaxf(v, 0.f);
        size_t idx = (size_t)row * ldc + col;
        if constexpr (EPI == 3) {
          ((float*)Cout)[idx] = v;
        } else {
          ((unsigned short*)Cout)[idx] = f2bf(v);
        }
      }
    }
  }
}

// ---------------------------------------------------------------------------
// Fused GEMM + residual + row-LayerNorm (or BatchNorm) epilogue.
// C = A*W^T + bias + resid  (x_new); MODE 0: write x_new fp32 to xout AND
// LN(x_new)*sa+sb -> lnout bf16.  MODE 1: BatchNorm(x_new) -> lnout only.
// BM=64, BN=256 (full row), 4 waves as 1x4, each wave 64x64.
// ---------------------------------------------------------------------------
template <int MODE>
__global__ __launch_bounds__(256) void gemm_ln(
    const unsigned short* __restrict__ A, const unsigned short* __restrict__ W,
    const float* __restrict__ bias, const float* __restrict__ resid,
    float* __restrict__ xout, const float* __restrict__ sa,
    const float* __restrict__ sb, unsigned short* __restrict__ lnout, int K) {
  constexpr int BM = 64, BK = 64;
  __shared__ unsigned short Alds[BM * BK];
  __shared__ unsigned short Blds[256 * BK];
  __shared__ float red[64][8];

  const int tid = threadIdx.x, wave = tid >> 6, lane = tid & 63;
  const int nwg = gridDim.x;
  const int swz = (blockIdx.x & 7) * (nwg >> 3) + (blockIdx.x >> 3);
  const int row0 = swz * BM;
  const int wc = wave;  // wave owns cols [wc*64, wc*64+64)
  const int fr = lane & 15, g4 = lane >> 4, ko = g4 * 8;
  const int swr = (fr & 7) << 3;
  const int l8 = lane >> 3;
  const int lkS = ((lane & 7) ^ l8) * 8;

  f32x4 acc[4][4];
#pragma unroll
  for (int i = 0; i < 4; ++i)
#pragma unroll
    for (int j = 0; j < 4; ++j) acc[i][j] = (f32x4)0.f;

  const int nkt = K / BK;
  for (int kt = 0; kt < nkt; ++kt) {
    __syncthreads();
#pragma unroll
    for (int j = 0; j < 2; ++j) {
      int ci = wave * 2 + j;
      const unsigned short* src = A + (size_t)(row0 + ci * 8 + l8) * K + kt * BK + lkS;
      GLD16(src, &Alds[ci * 512]);
    }
#pragma unroll
    for (int j = 0; j < 8; ++j) {
      int ci = wave * 8 + j;
      const unsigned short* src = W + (size_t)(ci * 8 + l8) * K + kt * BK + lkS;
      GLD16(src, &Blds[ci * 512]);
    }
    __syncthreads();
#pragma unroll
    for (int kk = 0; kk < 2; ++kk) {
      s16x8 af[4], bfr[4];
#pragma unroll
      for (int i = 0; i < 4; ++i)
        af[i] = *(const s16x8*)&Alds[(i * 16 + fr) * BK + ((kk * 32 + ko) ^ swr)];
#pragma unroll
      for (int j = 0; j < 4; ++j)
        bfr[j] = *(const s16x8*)&Blds[(wc * 64 + j * 16 + fr) * BK + ((kk * 32 + ko) ^ swr)];
#pragma unroll
      for (int i = 0; i < 4; ++i)
#pragma unroll
        for (int j = 0; j < 4; ++j)
          acc[i][j] =
              __builtin_amdgcn_mfma_f32_16x16x32_bf16(af[i], bfr[j], acc[i][j], 0, 0, 0);
    }
  }

  // epilogue: x_new = acc + bias + resid
  const int cc = lane & 15;
  float bv[4];
#pragma unroll
  for (int j = 0; j < 4; ++j) bv[j] = bias[wc * 64 + j * 16 + cc];
#pragma unroll
  for (int i = 0; i < 4; ++i)
#pragma unroll
    for (int j = 0; j < 4; ++j) {
      int col = wc * 64 + j * 16 + cc;
#pragma unroll
      for (int r = 0; r < 4; ++r) {
        size_t idx = (size_t)(row0 + i * 16 + g4 * 4 + r) * 256 + col;
        float v = acc[i][j][r] + bv[j] + resid[idx];
        acc[i][j][r] = v;
        if constexpr (MODE == 0) xout[idx] = v;
      }
    }

  if constexpr (MODE == 0) {
    // per-row sum / sumsq: reduce across the 16 cc-lanes, then cross-wave LDS
#pragma unroll
    for (int i = 0; i < 4; ++i)
#pragma unroll
      for (int r = 0; r < 4; ++r) {
        float s = acc[i][0][r] + acc[i][1][r] + acc[i][2][r] + acc[i][3][r];
        float q = acc[i][0][r] * acc[i][0][r] + acc[i][1][r] * acc[i][1][r] +
                  acc[i][2][r] * acc[i][2][r] + acc[i][3][r] * acc[i][3][r];
#pragma unroll
        for (int off = 1; off <= 8; off <<= 1) {
          s += __shfl_xor(s, off);
          q += __shfl_xor(q, off);
        }
        if (cc == 0) {
          int lrow = i * 16 + g4 * 4 + r;
          red[lrow][wc * 2] = s;
          red[lrow][wc * 2 + 1] = q;
        }
      }
    __syncthreads();
#pragma unroll
    for (int i = 0; i < 4; ++i)
#pragma unroll
      for (int r = 0; r < 4; ++r) {
        int lrow = i * 16 + g4 * 4 + r;
        float s = red[lrow][0] + red[lrow][2] + red[lrow][4] + red[lrow][6];
        float q = red[lrow][1] + red[lrow][3] + red[lrow][5] + red[lrow][7];
        float mean = s * (1.f / 256.f);
        float var = fmaxf(q - 256.f * mean * mean, 0.f) * (1.f / 255.f);
        float scl = 1.f / (sqrtf(var) + 1e-6f);
#pragma unroll
        for (int j = 0; j < 4; ++j) {
          int col = wc * 64 + j * 16 + cc;
          float o = sa[col] * (acc[i][j][r] - mean) * scl + sb[col];
          lnout[(size_t)(row0 + lrow) * 256 + col] = f2bf(o);
        }
      }
  } else {
    const float is = 0.9999950000374997f;  // 1/sqrt(1+1e-5)
#pragma unroll
    for (int i = 0; i < 4; ++i)
#pragma unroll
      for (int r = 0; r < 4; ++r) {
        int lrow = i * 16 + g4 * 4 + r;
#pragma unroll
        for (int j = 0; j < 4; ++j) {
          int col = wc * 64 + j * 16 + cc;
          float o = acc[i][j][r] * is * sa[col] + sb[col];
          lnout[(size_t)(row0 + lrow) * 256 + col] = f2bf(o);
        }
      }
  }
}

// ---------------------------------------------------------------------------
// Fused x+pos -> xbuf (fp32) and LayerNorm -> bufA (bf16). 1 wave per row.
// ---------------------------------------------------------------------------
__global__ __launch_bounds__(256) void addpos_ln(const f32x4* __restrict__ x,
                                                 const f32x4* __restrict__ pos,
                                                 const float* __restrict__ a,
                                                 const float* __restrict__ b,
                                                 f32x4* __restrict__ xout,
                                                 unsigned short* __restrict__ lnout) {
  const int wave = threadIdx.x >> 6, lane = threadIdx.x & 63;
  const size_t row = (size_t)blockIdx.x * 4 + wave;
  f32x4 v = x[row * 64 + lane] + pos[(row % 81) * 64 + lane];
  xout[row * 64 + lane] = v;
  float s = v[0] + v[1] + v[2] + v[3];
#pragma unroll
  for (int off = 32; off >= 1; off >>= 1) s += __shfl_xor(s, off);
  float mean = s * (1.f / 256.f);
  f32x4 d = v - mean;
  float sq = d[0] * d[0] + d[1] * d[1] + d[2] * d[2] + d[3] * d[3];
#pragma unroll
  for (int off = 32; off >= 1; off >>= 1) sq += __shfl_xor(sq, off);
  float var = sq * (1.f / 255.f);
  float scl = 1.f / (sqrtf(var) + 1e-6f);
  f32x4 av = *(const f32x4*)(a + lane * 4);
  f32x4 bv = *(const f32x4*)(b + lane * 4);
  u16x4 ob;
#pragma unroll
  for (int j = 0; j < 4; ++j) ob[j] = f2bf(av[j] * d[j] * scl + bv[j]);
  *(u16x4*)(lnout + row * 256 + lane * 4) = ob;
}

// ---------------------------------------------------------------------------
// MFMA strided sparse attention. 1 wave = 1 stream (b,h,m); 4 waves/block.
// ---------------------------------------------------------------------------
__global__ __launch_bounds__(256) void attn_mfma(const unsigned short* __restrict__ qkv,
                                                 unsigned short* __restrict__ o) {
  constexpr int LS = 40;  // LDS row stride in shorts
  const int wave = threadIdx.x >> 6, lane = threadIdx.x & 63;
  const int sid = blockIdx.x * 4 + wave;
  const int m = sid % 3, hh = (sid / 3) & 7, b = sid / 24;
  __shared__ unsigned short VtS[4][32 * LS];
  __shared__ unsigned short PlS[4][32 * LS];
  unsigned short* vt = VtS[wave];
  unsigned short* pl = PlS[wave];

  const unsigned short* base = qkv + (size_t)b * 81 * 768 + (size_t)m * 768 + hh * 32;
  const int fr = lane & 15;
  const int ko = (lane >> 4) * 8;
  const int g4 = lane >> 4;

  s16x8 qf[2], kf[2];
#pragma unroll
  for (int i = 0; i < 2; ++i) {
    int g = fr + 16 * i;
    if (g > 26) g = 26;
    const unsigned short* qp = base + (size_t)g * 2304 + ko;
    qf[i] = *(const s16x8*)qp;
    kf[i] = *(const s16x8*)(qp + 256);
  }

#pragma unroll
  for (int it = 0; it < 2; ++it) {
    int slot = it * 64 + lane;
    int g = slot >> 2, s = slot & 3;
    if (g < 27) {
      u16x8 v = *(const u16x8*)(base + (size_t)g * 2304 + 512 + s * 8);
#pragma unroll
      for (int j = 0; j < 8; ++j) vt[(s * 8 + j) * LS + g] = v[j];
    } else {
#pragma unroll
      for (int j = 0; j < 8; ++j) vt[(s * 8 + j) * LS + g] = 0;
    }
  }

  f32x4 sacc[2][2];
#pragma unroll
  for (int i = 0; i < 2; ++i)
#pragma unroll
    for (int j = 0; j < 2; ++j) sacc[i][j] = (f32x4)0.f;
#pragma unroll
  for (int i = 0; i < 2; ++i)
#pragma unroll
    for (int j = 0; j < 2; ++j)
      sacc[i][j] = __builtin_amdgcn_mfma_f32_16x16x32_bf16(qf[i], kf[j], sacc[i][j], 0, 0, 0);

  const float scale = 0.17677669529663687f;  // 1/sqrt(32)
  const bool v1 = fr < 11;
#pragma unroll
  for (int i = 0; i < 2; ++i) {
#pragma unroll
    for (int r = 0; r < 4; ++r) {
      float a0 = sacc[i][0][r] * scale;
      float a1 = v1 ? sacc[i][1][r] * scale : -3.0e38f;
      float mx = fmaxf(a0, a1);
#pragma unroll
      for (int off = 1; off <= 8; off <<= 1) mx = fmaxf(mx, __shfl_xor(mx, off));
      float e0 = __expf(a0 - mx);
      float e1 = v1 ? __expf(a1 - mx) : 0.f;
      float sm = e0 + e1;
#pragma unroll
      for (int off = 1; off <= 8; off <<= 1) sm += __shfl_xor(sm, off);
      float inv = 1.f / sm;
      int row = i * 16 + 4 * g4 + r;
      pl[row * LS + fr] = f2bf(e0 * inv);
      pl[row * LS + 16 + fr] = f2bf(e1 * inv);
    }
  }
  __syncthreads();

  s16x8 pf[2], vf[2];
#pragma unroll
  for (int i = 0; i < 2; ++i) pf[i] = *(const s16x8*)&pl[(fr + 16 * i) * LS + ko];
#pragma unroll
  for (int j = 0; j < 2; ++j) vf[j] = *(const s16x8*)&vt[(fr + 16 * j) * LS + ko];

  f32x4 oacc[2][2];
#pragma unroll
  for (int i = 0; i < 2; ++i)
#pragma unroll
    for (int j = 0; j < 2; ++j) oacc[i][j] = (f32x4)0.f;
#pragma unroll
  for (int i = 0; i < 2; ++i)
#pragma unroll
    for (int j = 0; j < 2; ++j)
      oacc[i][j] = __builtin_amdgcn_mfma_f32_16x16x32_bf16(pf[i], vf[j], oacc[i][j], 0, 0, 0);

  __syncthreads();
#pragma unroll
  for (int i = 0; i < 2; ++i)
#pragma unroll
    for (int j = 0; j < 2; ++j)
#pragma unroll
      for (int r = 0; r < 4; ++r)
        vt[(i * 16 + 4 * g4 + r) * LS + j * 16 + fr] = f2bf(oacc[i][j][r]);
  __syncthreads();

#pragma unroll
  for (int it = 0; it < 2; ++it) {
    int slot = it * 64 + lane;
    int g = slot >> 2, s = slot & 3;
    if (g < 27) {
      u16x8 v = *(const u16x8*)&vt[g * LS + s * 8];
      *(u16x8*)(o + (size_t)(b * 81 + m + 3 * g) * 256 + hh * 32 + s * 8) = v;
    }
  }
}

__global__ __launch_bounds__(256) void cvt_kernel(const f32x4* __restrict__ src,
                                                  u16x4* __restrict__ dst, int n4) {
  int i = blockIdx.x * 256 + threadIdx.x;
  if (i < n4) {
    f32x4 v = src[i];
    u16x4 o;
#pragma unroll
    for (int j = 0; j < 4; ++j) o[j] = f2bf(v[j]);
    dst[i] = o;
  }
}

// pack Wq|Wk|Wv -> wqkv3 bf16 [3][768][256]
__global__ __launch_bounds__(256) void qkvpack_kernel(const float* __restrict__ Wq,
                                                      const float* __restrict__ Wk,
                                                      const float* __restrict__ Wv,
                                                      u16x4* __restrict__ dst) {
  int i4 = blockIdx.x * 256 + threadIdx.x;
  int e = i4 * 4;
  int l = e / 196608;
  int r = (e / 256) % 768;
  int c = e & 255;
  const float* src;
  if (r < 256) src = Wq + (size_t)l * 65536 + r * 256 + c;
  else if (r < 512) src = Wk + (size_t)l * 65536 + (r - 256) * 256 + c;
  else src = Wv + (size_t)l * 65536 + (r - 512) * 256 + c;
  f32x4 v = *(const f32x4*)src;
  u16x4 o;
#pragma unroll
  for (int j = 0; j < 4; ++j) o[j] = f2bf(v[j]);
  dst[i4] = o;
}

__global__ __launch_bounds__(256) void biaspack_kernel(const float* __restrict__ bq,
                                                       const float* __restrict__ bk,
                                                       const float* __restrict__ bv,
                                                       float* __restrict__ dst) {
  int i = blockIdx.x * 256 + threadIdx.x;
  if (i >= 2304) return;
  int l = i / 768, r = i % 768;
  float v = (r < 256) ? bq[l * 256 + r] : (r < 512) ? bk[l * 256 + r - 256]
                                                    : bv[l * 256 + r - 512];
  dst[i] = v;
}

extern "C" void kernel_launch(void* const* d_in, const int* in_sizes, int n_in,
                              void* d_out, int out_size, void* d_ws, size_t ws_size,
                              hipStream_t stream) {
  const float* x      = (const float*)d_in[0];
  const float* pos    = (const float*)d_in[1];
  const float* ln1_a  = (const float*)d_in[2];
  const float* ln1_b  = (const float*)d_in[3];
  const float* Wq     = (const float*)d_in[4];
  const float* bq     = (const float*)d_in[5];
  const float* Wk     = (const float*)d_in[6];
  const float* bk     = (const float*)d_in[7];
  const float* Wv     = (const float*)d_in[8];
  const float* bv     = (const float*)d_in[9];
  const float* Wo     = (const float*)d_in[10];
  const float* bo     = (const float*)d_in[11];
  const float* ln2_a  = (const float*)d_in[12];
  const float* ln2_b  = (const float*)d_in[13];
  const float* W1     = (const float*)d_in[14];
  const float* b1     = (const float*)d_in[15];
  const float* W2     = (const float*)d_in[16];
  const float* b2     = (const float*)d_in[17];
  const float* bn_g   = (const float*)d_in[18];
  const float* bn_b   = (const float*)d_in[19];
  const float* conv_w = (const float*)d_in[20];
  const float* conv_b = (const float*)d_in[21];

  char* ws = (char*)d_ws;
  float* xbuf = (float*)ws;
  unsigned short* bufA = (unsigned short*)(ws + 84934656);
  unsigned short* bufB = (unsigned short*)(ws + 127401984);
  unsigned short* wqkv3 = (unsigned short*)(ws + 254803968);
  unsigned short* wo3 = wqkv3 + 589824;
  unsigned short* w13 = wo3 + 196608;
  unsigned short* w23 = w13 + 393216;
  unsigned short* cw  = w23 + 393216;
  float* qkvb3 = (float*)(ws + 254803968 + 3171840);

  auto cvt = [&](const float* s, unsigned short* d, int n) {
    int n4 = n / 4;
    cvt_kernel<<<(n4 + 255) / 256, 256, 0, stream>>>((const f32x4*)s, (u16x4*)d, n4);
  };
  qkvpack_kernel<<<576, 256, 0, stream>>>(Wq, Wk, Wv, (u16x4*)wqkv3);
  biaspack_kernel<<<9, 256, 0, stream>>>(bq, bk, bv, qkvb3);
  cvt(Wo, wo3, 196608);
  cvt(W1, w13, 393216);
  cvt(W2, w23, 393216);
  cvt(conv_w, cw, 13056);

  // x+pos -> xbuf ; LN1(layer0) -> bufA
  addpos_ln<<<20736, 256, 0, stream>>>((const f32x4*)x, (const f32x4*)pos, ln1_a, ln1_b,
                                       (f32x4*)xbuf, bufA);

  for (int l = 0; l < 3; ++l) {
    // fused QKV: one GEMM into [BT,768]
    gemm_bt<128, 0, 6><<<3888, 256, 0, stream>>>(bufA, wqkv3 + l * 196608,
                                                 qkvb3 + l * 768, (void*)bufB, 256, 768,
                                                 768, 768);
    attn_mfma<<<6144, 256, 0, stream>>>(bufB, bufA);
    // O-proj + residual -> xbuf ; LN2 -> bufA
    gemm_ln<0><<<1296, 256, 0, stream>>>(bufA, wo3 + l * 65536, bo + l * 256, xbuf, xbuf,
                                         ln2_a + l * 256, ln2_b + l * 256, bufA, 256);
    gemm_bt<128, 1, 4><<<2592, 256, 0, stream>>>(bufA, w13 + l * 131072, b1 + l * 512,
                                                 (void*)bufB, 256, 512, 512, 512);
    if (l < 2) {
      // FFN2 + residual -> xbuf ; LN1(l+1) -> bufA
      gemm_ln<0><<<1296, 256, 0, stream>>>(bufB, w23 + l * 131072, b2 + l * 256, xbuf,
                                           xbuf, ln1_a + (l + 1) * 256,
                                           ln1_b + (l + 1) * 256, bufA, 512);
    } else {
      // FFN2 + residual ; BatchNorm -> bufA (xbuf dead after this)
      gemm_ln<1><<<1296, 256, 0, stream>>>(bufB, w23 + l * 131072, b2 + l * 256, xbuf,
                                           nullptr, bn_g, bn_b, bufA, 512);
    }
  }
  gemm_bt<64, 3, 1><<<648, 256, 0, stream>>>(bufA, cw, conv_b, d_out, 256, 51, 51, 51);
}